// Round 1
// baseline (828.507 us; speedup 1.0000x reference)
//
#include <hip/hip_runtime.h>
#include <hip/hip_bf16.h>
#include <math.h>

typedef __attribute__((ext_vector_type(8))) short short8;
typedef __attribute__((ext_vector_type(4))) float f32x4;
typedef unsigned short u16;
typedef unsigned int u32;

__device__ __forceinline__ u16 f2bf(float f) {
  union { float f; u32 u; } x; x.f = f;
  return (u16)((x.u + 0x7fffu + ((x.u >> 16) & 1u)) >> 16);
}
// v_rcp-based gates: ~1ulp rcp error, negligible vs bf16 h quantization.
__device__ __forceinline__ float sigm(float v) {
  return __builtin_amdgcn_rcpf(1.0f + __expf(-v));
}
__device__ __forceinline__ float tanh_fast(float v) {
  // tanh(x) = 1 - 2/(1+e^{2x}); exact at +-inf, monotone, no branches.
  return 1.0f - 2.0f * __builtin_amdgcn_rcpf(1.0f + __expf(2.0f * v));
}

#define MFMA __builtin_amdgcn_mfma_f32_16x16x32_bf16
#define HS 262144  // 512*512 u16 per ring slot

// 16 x 16B loads (stride 64B), NO trailing wait: caller pairs with counted
// s_waitcnt vmcnt(N) so the two rf-halves share one latency exposure.
// gfx950 asm modifier order: `off offset:N sc0 [sc1]` (flags AFTER offset).
#define LDG16_BODY(FL)                                        \
    "global_load_dwordx4 %0, %16, off " FL "\n\t"             \
    "global_load_dwordx4 %1, %16, off offset:64 " FL "\n\t"   \
    "global_load_dwordx4 %2, %16, off offset:128 " FL "\n\t"  \
    "global_load_dwordx4 %3, %16, off offset:192 " FL "\n\t"  \
    "global_load_dwordx4 %4, %16, off offset:256 " FL "\n\t"  \
    "global_load_dwordx4 %5, %16, off offset:320 " FL "\n\t"  \
    "global_load_dwordx4 %6, %16, off offset:384 " FL "\n\t"  \
    "global_load_dwordx4 %7, %16, off offset:448 " FL "\n\t"  \
    "global_load_dwordx4 %8, %16, off offset:512 " FL "\n\t"  \
    "global_load_dwordx4 %9, %16, off offset:576 " FL "\n\t"  \
    "global_load_dwordx4 %10, %16, off offset:640 " FL "\n\t" \
    "global_load_dwordx4 %11, %16, off offset:704 " FL "\n\t" \
    "global_load_dwordx4 %12, %16, off offset:768 " FL "\n\t" \
    "global_load_dwordx4 %13, %16, off offset:832 " FL "\n\t" \
    "global_load_dwordx4 %14, %16, off offset:896 " FL "\n\t" \
    "global_load_dwordx4 %15, %16, off offset:960 " FL
#define LDG16_OPS(a, base)                                                     \
    : "=&v"(a[0]), "=&v"(a[1]), "=&v"(a[2]), "=&v"(a[3]), "=&v"(a[4]),         \
      "=&v"(a[5]), "=&v"(a[6]), "=&v"(a[7]), "=&v"(a[8]), "=&v"(a[9]),         \
      "=&v"(a[10]), "=&v"(a[11]), "=&v"(a[12]), "=&v"(a[13]), "=&v"(a[14]),    \
      "=&v"(a[15])                                                             \
    : "v"(base) : "memory"

__device__ __forceinline__ void ldg16nw_sc0(short8 a[16], const u16* base) {
  asm volatile(LDG16_BODY("sc0") LDG16_OPS(a, base));
}
__device__ __forceinline__ void ldg16nw_sc01(short8 a[16], const u16* base) {
  asm volatile(LDG16_BODY("sc0 sc1") LDG16_OPS(a, base));
}
// Counted waits. sched_barrier(0) after each: hipcc hoists register-only MFMA
// past inline-asm waitcnt despite the memory clobber (guide rule #18).
#define VMCNT16() do { asm volatile("s_waitcnt vmcnt(16)" ::: "memory"); \
                       __builtin_amdgcn_sched_barrier(0); } while (0)
#define VMCNT0()  do { asm volatile("s_waitcnt vmcnt(0)"  ::: "memory"); \
                       __builtin_amdgcn_sched_barrier(0); } while (0)

// MALL-direct store (cross-XCD visible by construction, no fences).
__device__ __forceinline__ void stg_sc01(u32* p, u32 v) {
  asm volatile("global_store_dword %0, %1, off sc0 sc1" :: "v"(p), "v"(v) : "memory");
}
// MALL-fresh flag load (sc1 bypasses the possibly-stale local L2).
__device__ __forceinline__ u32 ldflag(const u32* p) {
  u32 v;
  asm volatile("global_load_dword %0, %1, off sc0 sc1\n\t"
               "s_waitcnt vmcnt(0)" : "=v"(v) : "v"(p) : "memory");
  return v;
}

// Flag-array barrier: 32 per-WG step counters, polled by one 32-lane load +
// ballot per iteration. No atomic RMW anywhere on the steady-state path, so
// polls cannot queue ahead of the publishes at the MALL atomic unit.
// All waves of a WG poll independently (no entry syncthreads needed).
// Returns the min flag value (monotone -> caller may cache it to skip polls).
__device__ __forceinline__ u32 wait_ge(const u32* flags, u32 target, int lane) {
  const u32* p = flags + (lane & 31);
  u32 v;
  for (;;) {
    v = ldflag(p);
    if (__ballot(v >= target) == ~0ull) break;
    __builtin_amdgcn_s_sleep(1);
  }
  #pragma unroll
  for (int k = 16; k; k >>= 1) {
    u32 o = (u32)__shfl_xor((int)v, k);
    v = v < o ? v : o;
  }
  return v;
}

// Persistent fused 2-layer GRU, decoupled pipeline, zero steady-state fences.
// 256 WGs = 4 row-blocks x 2 layers x 32 col-blocks (1 WG/CU, co-resident).
// Own-recurrence h: plain stores -> local L2 dirty; sc0 loads (L1-bypass).
// Cross-XCD h1 handoff: sc0sc1 mirror stores -> MALL; sc0sc1 loads <- MALL.
__global__ __launch_bounds__(256, 1) void gru_fused(
    const float* __restrict__ xin, const float* __restrict__ h1in, const float* __restrict__ h2in,
    const float* __restrict__ Wih1, const float* __restrict__ Whh1,
    const float* __restrict__ bih1, const float* __restrict__ bhh1,
    const float* __restrict__ Wih2, const float* __restrict__ Whh2,
    const float* __restrict__ bih2, const float* __restrict__ bhh2,
    const float* __restrict__ Wfc, const float* __restrict__ bfc,
    float* __restrict__ out, u16* __restrict__ wsb, unsigned* __restrict__ barc)
{
  const int bid   = blockIdx.x;
  const int rb    = bid & 3;
  const int layer = (bid >> 2) & 1;
  const int cbl   = bid >> 3;
  const int n0    = cbl * 16;
  const int wid   = bid >> 2;
  const int tid   = threadIdx.x;
  const int w     = tid >> 6;
  const int lane  = tid & 63;
  const int quad  = lane >> 4;
  const int m16   = lane & 15;

  u16* x0  = wsb;                     // [512][576] bf16 (immutable after init)
  u16* x1  = x0 + 512 * 576;          // shifted copy
  u16* h1r = x1 + 512 * 576;          // 4-slot ring, local to layer-0 XCDs
  u16* h2r = h1r + 4 * HS;            // 4-slot ring, local to layer-1 XCDs
  u16* h1m = h2r + 4 * HS;            // 4-slot MALL mirror of h1 (cross-XCD)

  __shared__ short8 wlds[96 * 64];    // 96 KB weight fragments

  u32* f0    = (u32*)barc + rb * 32;        // producer flags (steps done)
  u32* f1    = (u32*)barc + 128 + rb * 32;  // consumer flags
  unsigned* cinit = barc + 512;

  const float* Wih = layer ? Wih2 : Wih1;
  const float* Whh = layer ? Whh2 : Whh1;
  const float* bih = layer ? bih2 : bih1;
  const float* bhh = layer ? bhh2 : bhh1;

  // ---------------- one-time init ----------------
  for (int i = wid * 256 + tid; i < 128 * 575; i += 64 * 256) {
    int r = i / 575, c = i - r * 575;
    int row = rb * 128 + r;
    u16 bv = f2bf(xin[row * 575 + c]);
    x0[row * 576 + c] = bv;
    if (c >= 1) x1[row * 576 + (c - 1)] = bv;
  }
  for (int i = wid * 256 + tid; i < 128 * 512; i += 64 * 256) {
    int r = i >> 9, c = i & 511;
    int row = rb * 128 + r;
    u16 h1v = f2bf(h1in[row * 512 + c]);
    h1r[3 * HS + row * 512 + c] = h1v;
    h2r[3 * HS + row * 512 + c] = f2bf(h2in[row * 512 + c]);
  }
  for (int i = tid; i < 96 * 64; i += 256) {
    int blk = i >> 6, l = i & 63;
    int s, gr;
    if (blk < 64) { s = blk & 31; gr = (blk >> 5) * 512; }   // r / z, K=1024
    else          { s = blk - 64; gr = 1024; }               // i_n (s<16) / h_n (s>=16)
    int n  = n0 + (l & 15);
    int k0 = s * 32 + (l >> 4) * 8;
    short8 pk;
    #pragma unroll
    for (int j = 0; j < 8; ++j) {
      int k = k0 + j;
      float v = (k < 512) ? Wih[(gr + n) * 512 + k] : Whh[(gr + n) * 512 + (k - 512)];
      pk[j] = (short)f2bf(v);
    }
    wlds[blk * 64 + l] = pk;
  }

  float hreg[2][4];
  const float* hin = layer ? h2in : h1in;
  #pragma unroll
  for (int rf = 0; rf < 2; ++rf)
    #pragma unroll
    for (int q = 0; q < 4; ++q)
      hreg[rf][q] = hin[(rb * 128 + (2 * w + rf) * 16 + quad * 4 + q) * 512 + n0 + m16];

  const int nn = n0 + m16;
  const float bias_r  = bih[nn] + bhh[nn];
  const float bias_z  = bih[512 + nn] + bhh[512 + nn];
  const float bias_in = bih[1024 + nn];
  const float bias_hn = bhh[1024 + nn];
  const float wfc  = Wfc[nn];
  const float bfcv = bfc[0];

  // init barrier: ONE-TIME release (wbl2) + acquire (inv) so init data is
  // MALL-visible everywhere; steady state then needs no cache maintenance.
  __syncthreads();
  if (tid == 0) {
    __builtin_amdgcn_fence(__ATOMIC_RELEASE, "agent");
    __hip_atomic_fetch_add(cinit, 1u, __ATOMIC_RELAXED, __HIP_MEMORY_SCOPE_AGENT);
    while (__hip_atomic_load(cinit, __ATOMIC_RELAXED, __HIP_MEMORY_SCOPE_AGENT) < 256u)
      __builtin_amdgcn_s_sleep(1);
    __builtin_amdgcn_fence(__ATOMIC_ACQUIRE, "agent");
  }
  __syncthreads();

  const int arow0 = rb * 128 + (2 * w) * 16 + m16;
  const int arow1 = arow0 + 16;

  if (layer == 0) {
    // =================== producer: h1(u) ===================
    u32 c1min = 0;  // monotone cache of consumer min-flag (skip slot polls)
    for (int u = 0; u < 64; ++u) {
      // ring slot u&3 free once consumers finished step u-4 (flag >= u-3)
      if (u >= 4 && c1min < (u32)(u - 3)) c1min = wait_ge(f1, (u32)(u - 3), lane);
      f32x4 acc[2][4] = {};
      // x-half: plain cached loads (immutable data), fills the peer-wait gap
      {
        const int c = u & 1;
        const u16* xc = c ? x1 : x0;
        const u32* pa0 = (const u32*)(xc + (size_t)arow0 * 576 + (u - c) + quad * 8);
        const u32* pa1 = (const u32*)(xc + (size_t)arow1 * 576 + (u - c) + quad * 8);
        #pragma unroll
        for (int s = 0; s < 16; ++s) {
          union { short8 v; u32 u4[4]; } a0, a1;
          #pragma unroll
          for (int j = 0; j < 4; ++j) { a0.u4[j] = pa0[s * 16 + j]; a1.u4[j] = pa1[s * 16 + j]; }
          short8 br = wlds[(s)      * 64 + lane];
          short8 bz = wlds[(32 + s) * 64 + lane];
          short8 bi = wlds[(64 + s) * 64 + lane];
          acc[0][0] = MFMA(a0.v, br, acc[0][0], 0, 0, 0);
          acc[1][0] = MFMA(a1.v, br, acc[1][0], 0, 0, 0);
          acc[0][1] = MFMA(a0.v, bz, acc[0][1], 0, 0, 0);
          acc[1][1] = MFMA(a1.v, bz, acc[1][1], 0, 0, 0);
          acc[0][2] = MFMA(a0.v, bi, acc[0][2], 0, 0, 0);
          acc[1][2] = MFMA(a1.v, bi, acc[1][2], 0, 0, 0);
        }
      }
      // wait: all 32 peers published h1(u-1)
      if (u > 0) wait_ge(f0, (u32)u, lane); else VMCNT0();
      // h-half: both rf issued back-to-back, one latency exposure (counted)
      {
        short8 a0[16], a1[16];
        const u16* hb = h1r + (size_t)((u + 3) & 3) * HS + quad * 8;
        ldg16nw_sc0(a0, hb + (size_t)arow0 * 512);
        ldg16nw_sc0(a1, hb + (size_t)arow1 * 512);
        VMCNT16();
        #pragma unroll
        for (int s = 0; s < 16; ++s) {
          short8 br = wlds[(16 + s) * 64 + lane];
          short8 bz = wlds[(48 + s) * 64 + lane];
          short8 bh = wlds[(80 + s) * 64 + lane];
          acc[0][0] = MFMA(a0[s], br, acc[0][0], 0, 0, 0);
          acc[0][1] = MFMA(a0[s], bz, acc[0][1], 0, 0, 0);
          acc[0][3] = MFMA(a0[s], bh, acc[0][3], 0, 0, 0);
        }
        VMCNT0();
        #pragma unroll
        for (int s = 0; s < 16; ++s) {
          short8 br = wlds[(16 + s) * 64 + lane];
          short8 bz = wlds[(48 + s) * 64 + lane];
          short8 bh = wlds[(80 + s) * 64 + lane];
          acc[1][0] = MFMA(a1[s], br, acc[1][0], 0, 0, 0);
          acc[1][1] = MFMA(a1[s], bz, acc[1][1], 0, 0, 0);
          acc[1][3] = MFMA(a1[s], bh, acc[1][3], 0, 0, 0);
        }
      }
      // gates + publish: paired u32 store (local ring) + sc0sc1 mirror (MALL)
      {
        u32* hw32 = (u32*)(h1r + (size_t)(u & 3) * HS);
        u32* hm   = (u32*)(h1m + (size_t)(u & 3) * HS);
        #pragma unroll
        for (int rf = 0; rf < 2; ++rf)
          #pragma unroll
          for (int q = 0; q < 4; ++q) {
            float rg = sigm(acc[rf][0][q] + bias_r);
            float zg = sigm(acc[rf][1][q] + bias_z);
            float ng = tanh_fast(acc[rf][2][q] + bias_in + rg * (acc[rf][3][q] + bias_hn));
            float hv = (1.0f - zg) * ng + zg * hreg[rf][q];
            hreg[rf][q] = hv;
            int row = rb * 128 + (2 * w + rf) * 16 + quad * 4 + q;
            u16 b = f2bf(hv);
            int pb = __shfl_xor((int)(u32)b, 1);
            if (!(m16 & 1)) {
              u32 pr = (u32)b | ((u32)(u16)pb << 16);
              int pi = (row * 512 + nn) >> 1;
              hw32[pi] = pr;
              stg_sc01(&hm[pi], pr);
            }
          }
      }
      asm volatile("s_waitcnt vmcnt(0)" ::: "memory");  // data landed before flag
      __syncthreads();
      if (tid == 0) stg_sc01(&f0[cbl], (u32)(u + 1));
    }
  } else {
    // =================== consumer: h2(v) + y(v) ===================
    for (int v = 0; v < 64; ++v) {
      f32x4 acc[2][4] = {};
      // peers-wait only; h2-half is producer-independent
      if (v > 0) wait_ge(f1, (u32)v, lane); else VMCNT0();
      {
        short8 a0[16], a1[16];
        const u16* hb = h2r + (size_t)((v + 3) & 3) * HS + quad * 8;
        ldg16nw_sc0(a0, hb + (size_t)arow0 * 512);
        ldg16nw_sc0(a1, hb + (size_t)arow1 * 512);
        VMCNT16();
        #pragma unroll
        for (int s = 0; s < 16; ++s) {
          short8 br = wlds[(16 + s) * 64 + lane];
          short8 bz = wlds[(48 + s) * 64 + lane];
          short8 bh = wlds[(80 + s) * 64 + lane];
          acc[0][0] = MFMA(a0[s], br, acc[0][0], 0, 0, 0);
          acc[0][1] = MFMA(a0[s], bz, acc[0][1], 0, 0, 0);
          acc[0][3] = MFMA(a0[s], bh, acc[0][3], 0, 0, 0);
        }
        VMCNT0();
        #pragma unroll
        for (int s = 0; s < 16; ++s) {
          short8 br = wlds[(16 + s) * 64 + lane];
          short8 bz = wlds[(48 + s) * 64 + lane];
          short8 bh = wlds[(80 + s) * 64 + lane];
          acc[1][0] = MFMA(a1[s], br, acc[1][0], 0, 0, 0);
          acc[1][1] = MFMA(a1[s], bz, acc[1][1], 0, 0, 0);
          acc[1][3] = MFMA(a1[s], bh, acc[1][3], 0, 0, 0);
        }
      }
      // now the producer-dependent part: h1(v) from MALL mirror
      wait_ge(f0, (u32)(v + 1), lane);
      {
        short8 a0[16], a1[16];
        const u16* hb = h1m + (size_t)(v & 3) * HS + quad * 8;
        ldg16nw_sc01(a0, hb + (size_t)arow0 * 512);
        ldg16nw_sc01(a1, hb + (size_t)arow1 * 512);
        VMCNT16();
        #pragma unroll
        for (int s = 0; s < 16; ++s) {
          short8 br = wlds[(s)      * 64 + lane];
          short8 bz = wlds[(32 + s) * 64 + lane];
          short8 bi = wlds[(64 + s) * 64 + lane];
          acc[0][0] = MFMA(a0[s], br, acc[0][0], 0, 0, 0);
          acc[0][1] = MFMA(a0[s], bz, acc[0][1], 0, 0, 0);
          acc[0][2] = MFMA(a0[s], bi, acc[0][2], 0, 0, 0);
        }
        VMCNT0();
        #pragma unroll
        for (int s = 0; s < 16; ++s) {
          short8 br = wlds[(s)      * 64 + lane];
          short8 bz = wlds[(32 + s) * 64 + lane];
          short8 bi = wlds[(64 + s) * 64 + lane];
          acc[1][0] = MFMA(a1[s], br, acc[1][0], 0, 0, 0);
          acc[1][1] = MFMA(a1[s], bz, acc[1][1], 0, 0, 0);
          acc[1][2] = MFMA(a1[s], bi, acc[1][2], 0, 0, 0);
        }
      }
      // gates + publish h2(v) (paired u32, local ring)
      {
        u32* hw32 = (u32*)(h2r + (size_t)(v & 3) * HS);
        #pragma unroll
        for (int rf = 0; rf < 2; ++rf)
          #pragma unroll
          for (int q = 0; q < 4; ++q) {
            float rg = sigm(acc[rf][0][q] + bias_r);
            float zg = sigm(acc[rf][1][q] + bias_z);
            float ng = tanh_fast(acc[rf][2][q] + bias_in + rg * (acc[rf][3][q] + bias_hn));
            float hv = (1.0f - zg) * ng + zg * hreg[rf][q];
            hreg[rf][q] = hv;
            int row = rb * 128 + (2 * w + rf) * 16 + quad * 4 + q;
            u16 b = f2bf(hv);
            int pb = __shfl_xor((int)(u32)b, 1);
            if (!(m16 & 1))
              hw32[(row * 512 + nn) >> 1] = (u32)b | ((u32)(u16)pb << 16);
          }
      }
      asm volatile("s_waitcnt vmcnt(0)" ::: "memory");
      __syncthreads();
      if (tid == 0) stg_sc01(&f1[cbl], (u32)(v + 1));
      // y after flag publish: atomics drain overlapped with next poll
      #pragma unroll
      for (int rf = 0; rf < 2; ++rf)
        #pragma unroll
        for (int q = 0; q < 4; ++q) {
          float yv = hreg[rf][q] * wfc;
          yv += __shfl_xor(yv, 1);
          yv += __shfl_xor(yv, 2);
          yv += __shfl_xor(yv, 4);
          yv += __shfl_xor(yv, 8);
          if (m16 == 0) {
            int row = rb * 128 + (2 * w + rf) * 16 + quad * 4 + q;
            atomicAdd(&out[row * 64 + v], yv + (n0 == 0 ? bfcv : 0.0f));
          }
        }
    }
  }

  // final hidden states from registers (fp32 exact)
  float* hout = out + 32768 + layer * (512 * 512);
  #pragma unroll
  for (int rf = 0; rf < 2; ++rf)
    #pragma unroll
    for (int q = 0; q < 4; ++q) {
      int row = rb * 128 + (2 * w + rf) * 16 + quad * 4 + q;
      hout[row * 512 + nn] = hreg[rf][q];
    }
}

extern "C" void kernel_launch(void* const* d_in, const int* in_sizes, int n_in,
                              void* d_out, int out_size, void* d_ws, size_t ws_size,
                              hipStream_t stream) {
  (void)in_sizes; (void)n_in; (void)out_size; (void)ws_size;
  hipMemsetAsync(d_out, 0, 32768 * sizeof(float), stream);   // y accumulators
  hipMemsetAsync(d_ws, 0, 4096, stream);                     // flags + init ctr
  unsigned* bar = (unsigned*)d_ws;
  u16* wsb = (u16*)((char*)d_ws + 4096);
  gru_fused<<<256, 256, 0, stream>>>(
      (const float*)d_in[0], (const float*)d_in[1], (const float*)d_in[2],
      (const float*)d_in[3], (const float*)d_in[4], (const float*)d_in[5], (const float*)d_in[6],
      (const float*)d_in[7], (const float*)d_in[8], (const float*)d_in[9], (const float*)d_in[10],
      (const float*)d_in[11], (const float*)d_in[12],
      (float*)d_out, wsb, bar);
}

// Round 5
// 801.912 us; speedup vs baseline: 1.0332x; 1.0332x over previous
//
#include <hip/hip_runtime.h>
#include <hip/hip_bf16.h>
#include <math.h>

typedef __attribute__((ext_vector_type(8))) short short8;
typedef __attribute__((ext_vector_type(4))) float f32x4;
typedef unsigned short u16;
typedef unsigned int u32;

__device__ __forceinline__ u16 f2bf(float f) {
  union { float f; u32 u; } x; x.f = f;
  return (u16)((x.u + 0x7fffu + ((x.u >> 16) & 1u)) >> 16);
}
// v_rcp-based gates: ~1ulp rcp error, negligible vs bf16 h quantization.
__device__ __forceinline__ float sigm(float v) {
  return __builtin_amdgcn_rcpf(1.0f + __expf(-v));
}
__device__ __forceinline__ float tanh_fast(float v) {
  return 1.0f - 2.0f * __builtin_amdgcn_rcpf(1.0f + __expf(2.0f * v));
}

#define MFMA __builtin_amdgcn_mfma_f32_16x16x32_bf16
#define HS 262144  // 512*512 u16 per ring slot

// 16 x 16B loads (stride 64B), NO trailing wait: caller pairs with counted
// s_waitcnt vmcnt(N) so the two rf-halves share one latency exposure.
// gfx950 asm modifier order: `off offset:N sc0 [sc1]` (flags AFTER offset).
#define LDG16_BODY(FL)                                        \
    "global_load_dwordx4 %0, %16, off " FL "\n\t"             \
    "global_load_dwordx4 %1, %16, off offset:64 " FL "\n\t"   \
    "global_load_dwordx4 %2, %16, off offset:128 " FL "\n\t"  \
    "global_load_dwordx4 %3, %16, off offset:192 " FL "\n\t"  \
    "global_load_dwordx4 %4, %16, off offset:256 " FL "\n\t"  \
    "global_load_dwordx4 %5, %16, off offset:320 " FL "\n\t"  \
    "global_load_dwordx4 %6, %16, off offset:384 " FL "\n\t"  \
    "global_load_dwordx4 %7, %16, off offset:448 " FL "\n\t"  \
    "global_load_dwordx4 %8, %16, off offset:512 " FL "\n\t"  \
    "global_load_dwordx4 %9, %16, off offset:576 " FL "\n\t"  \
    "global_load_dwordx4 %10, %16, off offset:640 " FL "\n\t" \
    "global_load_dwordx4 %11, %16, off offset:704 " FL "\n\t" \
    "global_load_dwordx4 %12, %16, off offset:768 " FL "\n\t" \
    "global_load_dwordx4 %13, %16, off offset:832 " FL "\n\t" \
    "global_load_dwordx4 %14, %16, off offset:896 " FL "\n\t" \
    "global_load_dwordx4 %15, %16, off offset:960 " FL
#define LDG16_OPS(a, base)                                                     \
    : "=&v"(a[0]), "=&v"(a[1]), "=&v"(a[2]), "=&v"(a[3]), "=&v"(a[4]),         \
      "=&v"(a[5]), "=&v"(a[6]), "=&v"(a[7]), "=&v"(a[8]), "=&v"(a[9]),         \
      "=&v"(a[10]), "=&v"(a[11]), "=&v"(a[12]), "=&v"(a[13]), "=&v"(a[14]),    \
      "=&v"(a[15])                                                             \
    : "v"(base) : "memory"

__device__ __forceinline__ void ldg16nw_sc0(short8 a[16], const u16* base) {
  asm volatile(LDG16_BODY("sc0") LDG16_OPS(a, base));
}
__device__ __forceinline__ void ldg16nw_sc01(short8 a[16], const u16* base) {
  asm volatile(LDG16_BODY("sc0 sc1") LDG16_OPS(a, base));
}
// Counted waits + sched_barrier (rule #18: hipcc hoists reg-only MFMA past
// inline-asm waitcnt despite the memory clobber).
#define VMCNT16() do { asm volatile("s_waitcnt vmcnt(16)" ::: "memory"); \
                       __builtin_amdgcn_sched_barrier(0); } while (0)
#define VMCNT0()  do { asm volatile("s_waitcnt vmcnt(0)"  ::: "memory"); \
                       __builtin_amdgcn_sched_barrier(0); } while (0)

// MALL-direct store for the cross-XCD mirror copy.
__device__ __forceinline__ void stg_sc01(u32* p, u32 v) {
  asm volatile("global_store_dword %0, %1, off sc0 sc1" :: "v"(p), "v"(v) : "memory");
}

// Poll two counters (MALL-resident, agent atomics), then workgroup barrier.
// NO cache fences: data freshness is guaranteed by sc-bit discipline.
__device__ __forceinline__ void waits_nf(unsigned* a, unsigned ta, unsigned* b, unsigned tb) {
  if (threadIdx.x == 0) {
    while (__hip_atomic_load(a, __ATOMIC_RELAXED, __HIP_MEMORY_SCOPE_AGENT) < ta)
      __builtin_amdgcn_s_sleep(1);
    while (__hip_atomic_load(b, __ATOMIC_RELAXED, __HIP_MEMORY_SCOPE_AGENT) < tb)
      __builtin_amdgcn_s_sleep(1);
  }
  __syncthreads();
}

// Per-lane 128-col dot of one A-fragment set (rows fixed per lane, cols
// 32*s + quad*8 + j) against the LDS-resident W_fc vector. Same-address LDS
// reads across the 16 lanes of a quad-group broadcast (conflict-free).
__device__ __forceinline__ float ydot(const short8 a[16], const float* wfcl, int quad) {
  float y = 0.0f;
  #pragma unroll
  for (int s = 0; s < 16; ++s) {
    const float4 wa = *(const float4*)&wfcl[32 * s + quad * 8];
    const float4 wb = *(const float4*)&wfcl[32 * s + quad * 8 + 4];
    union { short8 v; u32 u4[4]; } aa; aa.v = a[s];
    #pragma unroll
    for (int k = 0; k < 4; ++k) {
      union { u32 u; float f; } lo, hi;
      lo.u = aa.u4[k] << 16;
      hi.u = aa.u4[k] & 0xffff0000u;
      float w0 = (k < 2) ? ((k & 1) ? wa.z : wa.x) : ((k & 1) ? wb.z : wb.x);
      float w1 = (k < 2) ? ((k & 1) ? wa.w : wa.y) : ((k & 1) ? wb.w : wb.y);
      y = fmaf(lo.f, w0, y);
      y = fmaf(hi.f, w1, y);
    }
  }
  return y;
}

// Persistent fused 2-layer GRU, decoupled pipeline (PROVEN R0/R1 topology).
// 256 WGs = 4 row-blocks x 2 layers x 32 col-blocks (1 WG/CU, co-resident).
// Own-recurrence h: plain stores -> local L2 dirty; sc0 loads (L1-bypass).
// Cross-XCD h1 handoff: sc0sc1 mirror stores -> MALL; sc0sc1 loads <- MALL.
// NEW this round: y computed WITHOUT atomics — cbl==0 consumer WGs reduce
// y(v) from the h2(v) A-fragments they already load at step v+1 (plain
// stores, 1 writer per element). Removes 16384 32-way-contended fp32
// atomicAdds/step whose drain sat inside every consumer iteration.
__global__ __launch_bounds__(256, 1) void gru_fused(
    const float* __restrict__ xin, const float* __restrict__ h1in, const float* __restrict__ h2in,
    const float* __restrict__ Wih1, const float* __restrict__ Whh1,
    const float* __restrict__ bih1, const float* __restrict__ bhh1,
    const float* __restrict__ Wih2, const float* __restrict__ Whh2,
    const float* __restrict__ bih2, const float* __restrict__ bhh2,
    const float* __restrict__ Wfc, const float* __restrict__ bfc,
    float* __restrict__ out, u16* __restrict__ wsb, unsigned* __restrict__ barc)
{
  const int bid   = blockIdx.x;
  const int rb    = bid & 3;
  const int layer = (bid >> 2) & 1;
  const int cbl   = bid >> 3;
  const int n0    = cbl * 16;
  const int wid   = bid >> 2;
  const int tid   = threadIdx.x;
  const int w     = tid >> 6;
  const int lane  = tid & 63;
  const int quad  = lane >> 4;
  const int m16   = lane & 15;

  u16* x0  = wsb;                     // [512][576] bf16 (immutable after init)
  u16* x1  = x0 + 512 * 576;          // shifted copy
  u16* h1r = x1 + 512 * 576;          // 4-slot ring, local to layer-0 XCDs
  u16* h2r = h1r + 4 * HS;            // 4-slot ring, local to layer-1 XCDs
  u16* h1m = h2r + 4 * HS;            // 4-slot MALL mirror of h1 (cross-XCD)

  __shared__ short8 wlds[96 * 64];    // 96 KB weight fragments
  __shared__ float wfcl[512];         // W_fc vector (f32) for the y-dot

  unsigned* c0    = barc + rb * 32;
  unsigned* c1    = barc + 256 + rb * 32;
  unsigned* cinit = barc + 512;

  const float* Wih = layer ? Wih2 : Wih1;
  const float* Whh = layer ? Whh2 : Whh1;
  const float* bih = layer ? bih2 : bih1;
  const float* bhh = layer ? bhh2 : bhh1;

  // ---------------- one-time init ----------------
  for (int i = wid * 256 + tid; i < 128 * 575; i += 64 * 256) {
    int r = i / 575, c = i - r * 575;
    int row = rb * 128 + r;
    u16 bv = f2bf(xin[row * 575 + c]);
    x0[row * 576 + c] = bv;
    if (c >= 1) x1[row * 576 + (c - 1)] = bv;
  }
  for (int i = wid * 256 + tid; i < 128 * 512; i += 64 * 256) {
    int r = i >> 9, c = i & 511;
    int row = rb * 128 + r;
    u16 h1v = f2bf(h1in[row * 512 + c]);
    h1r[3 * HS + row * 512 + c] = h1v;
    h2r[3 * HS + row * 512 + c] = f2bf(h2in[row * 512 + c]);
  }
  for (int i = tid; i < 96 * 64; i += 256) {
    int blk = i >> 6, l = i & 63;
    int s, gr;
    if (blk < 64) { s = blk & 31; gr = (blk >> 5) * 512; }   // r / z, K=1024
    else          { s = blk - 64; gr = 1024; }               // i_n (s<16) / h_n (s>=16)
    int n  = n0 + (l & 15);
    int k0 = s * 32 + (l >> 4) * 8;
    short8 pk;
    #pragma unroll
    for (int j = 0; j < 8; ++j) {
      int k = k0 + j;
      float v = (k < 512) ? Wih[(gr + n) * 512 + k] : Whh[(gr + n) * 512 + (k - 512)];
      pk[j] = (short)f2bf(v);
    }
    wlds[blk * 64 + l] = pk;
  }
  for (int i = tid; i < 512; i += 256) wfcl[i] = Wfc[i];

  float hreg[2][4];
  const float* hin = layer ? h2in : h1in;
  #pragma unroll
  for (int rf = 0; rf < 2; ++rf)
    #pragma unroll
    for (int q = 0; q < 4; ++q)
      hreg[rf][q] = hin[(rb * 128 + (2 * w + rf) * 16 + quad * 4 + q) * 512 + n0 + m16];

  const int nn = n0 + m16;
  const float bias_r  = bih[nn] + bhh[nn];
  const float bias_z  = bih[512 + nn] + bhh[512 + nn];
  const float bias_in = bih[1024 + nn];
  const float bias_hn = bhh[1024 + nn];
  const float bfcv = bfc[0];

  // init barrier: ONE-TIME release (wbl2) + acquire (inv) so init data is
  // MALL-visible everywhere; steady state then needs no cache maintenance.
  __syncthreads();
  if (tid == 0) {
    __builtin_amdgcn_fence(__ATOMIC_RELEASE, "agent");
    __hip_atomic_fetch_add(cinit, 1u, __ATOMIC_RELAXED, __HIP_MEMORY_SCOPE_AGENT);
    while (__hip_atomic_load(cinit, __ATOMIC_RELAXED, __HIP_MEMORY_SCOPE_AGENT) < 256u)
      __builtin_amdgcn_s_sleep(1);
    __builtin_amdgcn_fence(__ATOMIC_ACQUIRE, "agent");
  }
  __syncthreads();

  const int arow0 = rb * 128 + (2 * w) * 16 + m16;
  const int arow1 = arow0 + 16;

  if (layer == 0) {
    // =================== producer: h1(u) ===================
    for (int u = 0; u < 64; ++u) {
      f32x4 acc[2][4] = {};
      // x-half: plain cached loads (immutable data, L1-friendly), pre-wait
      {
        const int c = u & 1;
        const u16* xc = c ? x1 : x0;
        const u32* pa0 = (const u32*)(xc + (size_t)arow0 * 576 + (u - c) + quad * 8);
        const u32* pa1 = (const u32*)(xc + (size_t)arow1 * 576 + (u - c) + quad * 8);
        #pragma unroll
        for (int s = 0; s < 16; ++s) {
          union { short8 v; u32 u4[4]; } a0, a1;
          #pragma unroll
          for (int j = 0; j < 4; ++j) { a0.u4[j] = pa0[s * 16 + j]; a1.u4[j] = pa1[s * 16 + j]; }
          short8 br = wlds[(s)      * 64 + lane];
          short8 bz = wlds[(32 + s) * 64 + lane];
          short8 bi = wlds[(64 + s) * 64 + lane];
          acc[0][0] = MFMA(a0.v, br, acc[0][0], 0, 0, 0);
          acc[1][0] = MFMA(a1.v, br, acc[1][0], 0, 0, 0);
          acc[0][1] = MFMA(a0.v, bz, acc[0][1], 0, 0, 0);
          acc[1][1] = MFMA(a1.v, bz, acc[1][1], 0, 0, 0);
          acc[0][2] = MFMA(a0.v, bi, acc[0][2], 0, 0, 0);
          acc[1][2] = MFMA(a1.v, bi, acc[1][2], 0, 0, 0);
        }
      }
      // wait: peers done h1(u-1); ring slot u&3 free (layer-1 past u-4)
      waits_nf(c0, 32u * (unsigned)u, c1, u >= 4 ? 32u * (unsigned)(u - 3) : 0u);
      // h-half: both rf issued back-to-back, one latency exposure (counted)
      {
        short8 a0[16], a1[16];
        const u16* hb = h1r + (size_t)((u + 3) & 3) * HS + quad * 8;
        ldg16nw_sc0(a0, hb + (size_t)arow0 * 512);
        ldg16nw_sc0(a1, hb + (size_t)arow1 * 512);
        VMCNT16();
        #pragma unroll
        for (int s = 0; s < 16; ++s) {
          short8 br = wlds[(16 + s) * 64 + lane];
          short8 bz = wlds[(48 + s) * 64 + lane];
          short8 bh = wlds[(80 + s) * 64 + lane];
          acc[0][0] = MFMA(a0[s], br, acc[0][0], 0, 0, 0);
          acc[0][1] = MFMA(a0[s], bz, acc[0][1], 0, 0, 0);
          acc[0][3] = MFMA(a0[s], bh, acc[0][3], 0, 0, 0);
        }
        VMCNT0();
        #pragma unroll
        for (int s = 0; s < 16; ++s) {
          short8 br = wlds[(16 + s) * 64 + lane];
          short8 bz = wlds[(48 + s) * 64 + lane];
          short8 bh = wlds[(80 + s) * 64 + lane];
          acc[1][0] = MFMA(a1[s], br, acc[1][0], 0, 0, 0);
          acc[1][1] = MFMA(a1[s], bz, acc[1][1], 0, 0, 0);
          acc[1][3] = MFMA(a1[s], bh, acc[1][3], 0, 0, 0);
        }
      }
      // gates + publish: paired u32 store (local ring) + sc0sc1 mirror (MALL)
      {
        u32* hw32 = (u32*)(h1r + (size_t)(u & 3) * HS);
        u32* hm   = (u32*)(h1m + (size_t)(u & 3) * HS);
        #pragma unroll
        for (int rf = 0; rf < 2; ++rf)
          #pragma unroll
          for (int q = 0; q < 4; ++q) {
            float rg = sigm(acc[rf][0][q] + bias_r);
            float zg = sigm(acc[rf][1][q] + bias_z);
            float ng = tanh_fast(acc[rf][2][q] + bias_in + rg * (acc[rf][3][q] + bias_hn));
            float hv = (1.0f - zg) * ng + zg * hreg[rf][q];
            hreg[rf][q] = hv;
            int row = rb * 128 + (2 * w + rf) * 16 + quad * 4 + q;
            u16 b = f2bf(hv);
            int pb = __shfl_xor((int)(u32)b, 1);
            if (!(m16 & 1)) {
              u32 pr = (u32)b | ((u32)(u16)pb << 16);
              int pi = (row * 512 + nn) >> 1;
              hw32[pi] = pr;
              stg_sc01(&hm[pi], pr);
            }
          }
      }
      asm volatile("s_waitcnt vmcnt(0)" ::: "memory");  // mirror at MALL before inc
      __syncthreads();
      if (tid == 0)
        __hip_atomic_fetch_add(c0, 1u, __ATOMIC_RELAXED, __HIP_MEMORY_SCOPE_AGENT);
    }
  } else {
    // =================== consumer: h2(v) + y ===================
    const bool ywg = (cbl == 0);   // one col-WG per rb owns the y output
    for (int v = 0; v < 64; ++v) {
      f32x4 acc[2][4] = {};
      waits_nf(c1, 32u * (unsigned)v, c0, 32u * (unsigned)(v + 1));
      float ya0 = 0.0f, ya1 = 0.0f;
      // h2-half: sc0 (local L2 dirty = fresh); rf-paired counted waits.
      // The loaded fragments ARE h2(v-1) over all 512 cols -> y(v-1) dot.
      {
        short8 a0[16], a1[16];
        const u16* hb = h2r + (size_t)((v + 3) & 3) * HS + quad * 8;
        ldg16nw_sc0(a0, hb + (size_t)arow0 * 512);
        ldg16nw_sc0(a1, hb + (size_t)arow1 * 512);
        VMCNT16();
        #pragma unroll
        for (int s = 0; s < 16; ++s) {
          short8 br = wlds[(16 + s) * 64 + lane];
          short8 bz = wlds[(48 + s) * 64 + lane];
          short8 bh = wlds[(80 + s) * 64 + lane];
          acc[0][0] = MFMA(a0[s], br, acc[0][0], 0, 0, 0);
          acc[0][1] = MFMA(a0[s], bz, acc[0][1], 0, 0, 0);
          acc[0][3] = MFMA(a0[s], bh, acc[0][3], 0, 0, 0);
        }
        if (ywg && v > 0) ya0 = ydot(a0, wfcl, quad);
        VMCNT0();
        #pragma unroll
        for (int s = 0; s < 16; ++s) {
          short8 br = wlds[(16 + s) * 64 + lane];
          short8 bz = wlds[(48 + s) * 64 + lane];
          short8 bh = wlds[(80 + s) * 64 + lane];
          acc[1][0] = MFMA(a1[s], br, acc[1][0], 0, 0, 0);
          acc[1][1] = MFMA(a1[s], bz, acc[1][1], 0, 0, 0);
          acc[1][3] = MFMA(a1[s], bh, acc[1][3], 0, 0, 0);
        }
        if (ywg && v > 0) ya1 = ydot(a1, wfcl, quad);
      }
      // h1-half: sc0sc1 (MALL-direct, fresh by construction, no inv needed)
      {
        short8 b0[16], b1[16];
        const u16* hb = h1m + (size_t)(v & 3) * HS + quad * 8;
        ldg16nw_sc01(b0, hb + (size_t)arow0 * 512);
        ldg16nw_sc01(b1, hb + (size_t)arow1 * 512);
        VMCNT16();
        #pragma unroll
        for (int s = 0; s < 16; ++s) {
          short8 br = wlds[(s)      * 64 + lane];
          short8 bz = wlds[(32 + s) * 64 + lane];
          short8 bi = wlds[(64 + s) * 64 + lane];
          acc[0][0] = MFMA(b0[s], br, acc[0][0], 0, 0, 0);
          acc[0][1] = MFMA(b0[s], bz, acc[0][1], 0, 0, 0);
          acc[0][2] = MFMA(b0[s], bi, acc[0][2], 0, 0, 0);
        }
        VMCNT0();
        #pragma unroll
        for (int s = 0; s < 16; ++s) {
          short8 br = wlds[(s)      * 64 + lane];
          short8 bz = wlds[(32 + s) * 64 + lane];
          short8 bi = wlds[(64 + s) * 64 + lane];
          acc[1][0] = MFMA(b1[s], br, acc[1][0], 0, 0, 0);
          acc[1][1] = MFMA(b1[s], bz, acc[1][1], 0, 0, 0);
          acc[1][2] = MFMA(b1[s], bi, acc[1][2], 0, 0, 0);
        }
      }
      // gates + publish h2(v) (paired u32, local ring)
      {
        u32* hw32 = (u32*)(h2r + (size_t)(v & 3) * HS);
        #pragma unroll
        for (int rf = 0; rf < 2; ++rf)
          #pragma unroll
          for (int q = 0; q < 4; ++q) {
            float rg = sigm(acc[rf][0][q] + bias_r);
            float zg = sigm(acc[rf][1][q] + bias_z);
            float ng = tanh_fast(acc[rf][2][q] + bias_in + rg * (acc[rf][3][q] + bias_hn));
            float hv = (1.0f - zg) * ng + zg * hreg[rf][q];
            hreg[rf][q] = hv;
            int row = rb * 128 + (2 * w + rf) * 16 + quad * 4 + q;
            u16 b = f2bf(hv);
            int pb = __shfl_xor((int)(u32)b, 1);
            if (!(m16 & 1))
              hw32[(row * 512 + nn) >> 1] = (u32)b | ((u32)(u16)pb << 16);
          }
      }
      asm volatile("s_waitcnt vmcnt(0)" ::: "memory");
      __syncthreads();
      if (tid == 0)
        __hip_atomic_fetch_add(c1, 1u, __ATOMIC_RELAXED, __HIP_MEMORY_SCOPE_AGENT);
      // y(v-1) fold + plain store (single writer per element, NO atomics);
      // stores drain overlapped with the next step's poll/compute.
      if (ywg && v > 0) {
        ya0 += __shfl_xor(ya0, 16); ya0 += __shfl_xor(ya0, 32);
        ya1 += __shfl_xor(ya1, 16); ya1 += __shfl_xor(ya1, 32);
        if (quad == 0) {
          out[arow0 * 64 + (v - 1)] = ya0 + bfcv;
          out[arow1 * 64 + (v - 1)] = ya1 + bfcv;
        }
      }
    }
    // epilogue: y(63) from the final h2 ring slot (local L2)
    if (ywg) {
      waits_nf(c1, 32u * 64u, c1, 32u * 64u);
      short8 a0[16], a1[16];
      const u16* hb = h2r + (size_t)3 * HS + quad * 8;
      ldg16nw_sc0(a0, hb + (size_t)arow0 * 512);
      ldg16nw_sc0(a1, hb + (size_t)arow1 * 512);
      VMCNT16();
      float ya0 = ydot(a0, wfcl, quad);
      VMCNT0();
      float ya1 = ydot(a1, wfcl, quad);
      ya0 += __shfl_xor(ya0, 16); ya0 += __shfl_xor(ya0, 32);
      ya1 += __shfl_xor(ya1, 16); ya1 += __shfl_xor(ya1, 32);
      if (quad == 0) {
        out[arow0 * 64 + 63] = ya0 + bfcv;
        out[arow1 * 64 + 63] = ya1 + bfcv;
      }
    }
  }

  // final hidden states from registers (fp32 exact)
  float* hout = out + 32768 + layer * (512 * 512);
  #pragma unroll
  for (int rf = 0; rf < 2; ++rf)
    #pragma unroll
    for (int q = 0; q < 4; ++q) {
      int row = rb * 128 + (2 * w + rf) * 16 + quad * 4 + q;
      hout[row * 512 + nn] = hreg[rf][q];
    }
}

extern "C" void kernel_launch(void* const* d_in, const int* in_sizes, int n_in,
                              void* d_out, int out_size, void* d_ws, size_t ws_size,
                              hipStream_t stream) {
  (void)in_sizes; (void)n_in; (void)out_size; (void)ws_size;
  hipMemsetAsync(d_out, 0, 32768 * sizeof(float), stream);   // y region
  hipMemsetAsync(d_ws, 0, 4096, stream);                     // arrival counters
  unsigned* bar = (unsigned*)d_ws;
  u16* wsb = (u16*)((char*)d_ws + 4096);
  gru_fused<<<256, 256, 0, stream>>>(
      (const float*)d_in[0], (const float*)d_in[1], (const float*)d_in[2],
      (const float*)d_in[3], (const float*)d_in[4], (const float*)d_in[5], (const float*)d_in[6],
      (const float*)d_in[7], (const float*)d_in[8], (const float*)d_in[9], (const float*)d_in[10],
      (const float*)d_in[11], (const float*)d_in[12],
      (float*)d_out, wsb, bar);
}